// Round 1
// baseline (498.877 us; speedup 1.0000x reference)
//
#include <hip/hip_runtime.h>
#include <stdint.h>

#define D_MODEL   1024
#define D_HIDDEN  4096
#define NBANKS    16
#define NTOK      4096      // 4 * 1024 tokens

#define BM 128
#define BN 128
#define BK 32
#define LDSK 56             // padded LDS row stride in bf16 elems (112 B, 16B-mult)

typedef __attribute__((ext_vector_type(8))) short bf16x8;
typedef __attribute__((ext_vector_type(4))) float f32x4;

__device__ __forceinline__ unsigned short f2bf(float f) {
  unsigned u = __builtin_bit_cast(unsigned, f);
  u += 0x7FFFu + ((u >> 16) & 1u);      // round-to-nearest-even
  return (unsigned short)(u >> 16);
}

// ---------------- zero output + counts ----------------
__global__ __launch_bounds__(256) void zero_out_k(float4* __restrict__ out4,
                                                  int* __restrict__ counts) {
  size_t i = (size_t)blockIdx.x * 256 + threadIdx.x;
  out4[i] = make_float4(0.f, 0.f, 0.f, 0.f);
  if (blockIdx.x == 0 && threadIdx.x < NBANKS) counts[threadIdx.x] = 0;
}

// ---------------- router: softmax over 16 banks, top-2 ----------------
__global__ __launch_bounds__(64) void router_k(const float* __restrict__ x,
                                               const float* __restrict__ Wr,
                                               const float* __restrict__ br,
                                               int* __restrict__ topIdx,
                                               float* __restrict__ topGate) {
  const int t = blockIdx.x;
  const int l = threadIdx.x;
  const float* xr = x + (size_t)t * D_MODEL;

  float acc[NBANKS];
#pragma unroll
  for (int e = 0; e < NBANKS; ++e) acc[e] = 0.f;

  for (int d = l; d < D_MODEL; d += 64) {
    const float xv = xr[d];
    const float* wrow = Wr + (size_t)d * NBANKS;
#pragma unroll
    for (int e = 0; e < NBANKS; ++e) acc[e] += xv * wrow[e];
  }
#pragma unroll
  for (int e = 0; e < NBANKS; ++e) {
#pragma unroll
    for (int m = 1; m < 64; m <<= 1) acc[e] += __shfl_xor(acc[e], m, 64);
  }
#pragma unroll
  for (int e = 0; e < NBANKS; ++e) acc[e] += br[e];

  if (l == 0) {
    float mx = acc[0];
#pragma unroll
    for (int e = 1; e < NBANKS; ++e) mx = fmaxf(mx, acc[e]);
    float p[NBANKS];
    float s = 0.f;
#pragma unroll
    for (int e = 0; e < NBANKS; ++e) { p[e] = expf(acc[e] - mx); s += p[e]; }
    int i0 = 0; float v0 = p[0];
#pragma unroll
    for (int e = 1; e < NBANKS; ++e) if (p[e] > v0) { v0 = p[e]; i0 = e; }
    int i1 = -1; float v1 = -1.f;
#pragma unroll
    for (int e = 0; e < NBANKS; ++e) if (e != i0 && p[e] > v1) { v1 = p[e]; i1 = e; }
    const float inv = 1.f / s;
    topIdx[2 * t]     = i0;
    topIdx[2 * t + 1] = i1;
    topGate[2 * t]     = v0 * inv;
    topGate[2 * t + 1] = v1 * inv;
  }
}

// ---------------- build per-bank token lists ----------------
__global__ __launch_bounds__(256) void build_lists_k(const int* __restrict__ topIdx,
                                                     const float* __restrict__ topGate,
                                                     int* __restrict__ counts,
                                                     int* __restrict__ rowlist,
                                                     float* __restrict__ gatelist) {
  const int t = blockIdx.x * 256 + threadIdx.x;
  if (t >= NTOK) return;
#pragma unroll
  for (int k = 0; k < 2; ++k) {
    const int e = topIdx[2 * t + k];
    const int p = atomicAdd(&counts[e], 1);
    rowlist[e * NTOK + p]  = t;
    gatelist[e * NTOK + p] = topGate[2 * t + k];
  }
}

__global__ void scan_k(const int* __restrict__ counts, int* __restrict__ bankOff) {
  if (threadIdx.x == 0) {
    int s = 0;
#pragma unroll
    for (int e = 0; e < NBANKS; ++e) { bankOff[e] = s; s += counts[e]; }
    bankOff[NBANKS] = s;
  }
}

// ---------------- GEMM1: H = relu(gather(X) @ W1[e] + b1[e]) ----------------
__global__ __launch_bounds__(256) void gemm1_k(const float* __restrict__ X,
                                               const float* __restrict__ W1,
                                               const float* __restrict__ b1,
                                               const int* __restrict__ counts,
                                               const int* __restrict__ bankOff,
                                               const int* __restrict__ rowlist,
                                               unsigned short* __restrict__ H) {
  const int e   = blockIdx.z;
  const int cnt = counts[e];
  const int m0  = blockIdx.y * BM;
  if (m0 >= cnt) return;
  const int n0  = blockIdx.x * BN;

  const int tid  = threadIdx.x;
  const int lane = tid & 63;
  const int w    = tid >> 6;
  const int wm   = (w >> 1) * 64;
  const int wn   = (w & 1) * 64;

  __shared__ unsigned short Xs[BM][LDSK];
  __shared__ unsigned short Ws[BN][LDSK];

  // A staging coords: 2 threads per row, 16 f32 each
  const int ar = tid >> 1;
  const int ak = (tid & 1) * 16;
  const int gi = min(m0 + ar, cnt - 1);
  const int tok = rowlist[e * NTOK + gi];
  const float* Arow = X + (size_t)tok * D_MODEL;

  // B staging coords
  const int bn = tid & 127;
  const int bg = tid >> 7;   // 0 or 1
  const float* Wb = W1 + (size_t)e * D_MODEL * D_HIDDEN;

  f32x4 acc[4][4];
#pragma unroll
  for (int i = 0; i < 4; ++i)
#pragma unroll
    for (int j = 0; j < 4; ++j)
#pragma unroll
      for (int r = 0; r < 4; ++r) acc[i][j][r] = 0.f;

  for (int k0 = 0; k0 < D_MODEL; k0 += BK) {
    // stage A: 16 f32 -> bf16, two b128 stores
    {
      const float4* src = (const float4*)(Arow + k0 + ak);
      const float4 f0 = src[0], f1 = src[1], f2 = src[2], f3 = src[3];
      bf16x8 v0, v1;
      v0[0]=(short)f2bf(f0.x); v0[1]=(short)f2bf(f0.y); v0[2]=(short)f2bf(f0.z); v0[3]=(short)f2bf(f0.w);
      v0[4]=(short)f2bf(f1.x); v0[5]=(short)f2bf(f1.y); v0[6]=(short)f2bf(f1.z); v0[7]=(short)f2bf(f1.w);
      v1[0]=(short)f2bf(f2.x); v1[1]=(short)f2bf(f2.y); v1[2]=(short)f2bf(f2.z); v1[3]=(short)f2bf(f2.w);
      v1[4]=(short)f2bf(f3.x); v1[5]=(short)f2bf(f3.y); v1[6]=(short)f2bf(f3.z); v1[7]=(short)f2bf(f3.w);
      *((bf16x8*)&Xs[ar][ak])     = v0;
      *((bf16x8*)&Xs[ar][ak + 8]) = v1;
    }
    // stage B: transposed (n-major) with packed b64 stores
#pragma unroll
    for (int i = 0; i < 4; ++i) {
      const int kb = bg * 4 + i * 8;     // {0,8,16,24} or {4,12,20,28}
      const float* wp = Wb + (size_t)(k0 + kb) * D_HIDDEN + n0 + bn;
      const float a0 = wp[0];
      const float a1 = wp[D_HIDDEN];
      const float a2 = wp[2 * D_HIDDEN];
      const float a3 = wp[3 * D_HIDDEN];
      const unsigned long long pv =
          (unsigned long long)f2bf(a0)
        | ((unsigned long long)f2bf(a1) << 16)
        | ((unsigned long long)f2bf(a2) << 32)
        | ((unsigned long long)f2bf(a3) << 48);
      *((unsigned long long*)&Ws[bn][kb]) = pv;
    }
    __syncthreads();

    const int fr = lane & 15;
    const int fc = (lane >> 4) * 8;
    bf16x8 af[4], bfv[4];
#pragma unroll
    for (int mb = 0; mb < 4; ++mb) af[mb]  = *(const bf16x8*)&Xs[wm + mb * 16 + fr][fc];
#pragma unroll
    for (int nb = 0; nb < 4; ++nb) bfv[nb] = *(const bf16x8*)&Ws[wn + nb * 16 + fr][fc];
#pragma unroll
    for (int mb = 0; mb < 4; ++mb)
#pragma unroll
      for (int nb = 0; nb < 4; ++nb)
        acc[mb][nb] = __builtin_amdgcn_mfma_f32_16x16x32_bf16(af[mb], bfv[nb], acc[mb][nb], 0, 0, 0);
    __syncthreads();
  }

  // epilogue: relu(acc + b1) -> H (bf16)
  const int hb = bankOff[e] + m0;
#pragma unroll
  for (int nb = 0; nb < 4; ++nb) {
    const int col = n0 + wn + nb * 16 + (lane & 15);
    const float bias = b1[e * D_HIDDEN + col];
#pragma unroll
    for (int mb = 0; mb < 4; ++mb)
#pragma unroll
      for (int r = 0; r < 4; ++r) {
        const int rowT = wm + mb * 16 + (lane >> 4) * 4 + r;
        if (m0 + rowT < cnt) {
          float v = acc[mb][nb][r] + bias;
          v = fmaxf(v, 0.f);
          H[(size_t)(hb + rowT) * D_HIDDEN + col] = f2bf(v);
        }
      }
  }
}

// ---------------- GEMM2: out += gate * (H @ W2[e] + b2[e]) ----------------
__global__ __launch_bounds__(256) void gemm2_k(const unsigned short* __restrict__ H,
                                               const float* __restrict__ W2,
                                               const float* __restrict__ b2,
                                               const int* __restrict__ counts,
                                               const int* __restrict__ bankOff,
                                               const int* __restrict__ rowlist,
                                               const float* __restrict__ gatelist,
                                               float* __restrict__ out) {
  const int e   = blockIdx.z;
  const int cnt = counts[e];
  const int m0  = blockIdx.y * BM;
  if (m0 >= cnt) return;
  const int n0  = blockIdx.x * BN;

  const int tid  = threadIdx.x;
  const int lane = tid & 63;
  const int w    = tid >> 6;
  const int wm   = (w >> 1) * 64;
  const int wn   = (w & 1) * 64;

  __shared__ unsigned short Xs[BM][LDSK];
  __shared__ unsigned short Ws[BN][LDSK];

  const int ar = tid >> 1;
  const int ak = (tid & 1) * 16;
  const int hb = bankOff[e];
  const int gi = hb + min(m0 + ar, cnt - 1);
  const unsigned short* Arow = H + (size_t)gi * D_HIDDEN;

  const int bn = tid & 127;
  const int bg = tid >> 7;
  const float* Wb = W2 + (size_t)e * D_HIDDEN * D_MODEL;

  f32x4 acc[4][4];
#pragma unroll
  for (int i = 0; i < 4; ++i)
#pragma unroll
    for (int j = 0; j < 4; ++j)
#pragma unroll
      for (int r = 0; r < 4; ++r) acc[i][j][r] = 0.f;

  for (int k0 = 0; k0 < D_HIDDEN; k0 += BK) {
    // stage A: H already bf16, two b128 copies
    *((bf16x8*)&Xs[ar][ak])     = *(const bf16x8*)(Arow + k0 + ak);
    *((bf16x8*)&Xs[ar][ak + 8]) = *(const bf16x8*)(Arow + k0 + ak + 8);
    // stage B: transposed with packed b64 stores
#pragma unroll
    for (int i = 0; i < 4; ++i) {
      const int kb = bg * 4 + i * 8;
      const float* wp = Wb + (size_t)(k0 + kb) * D_MODEL + n0 + bn;
      const float a0 = wp[0];
      const float a1 = wp[D_MODEL];
      const float a2 = wp[2 * D_MODEL];
      const float a3 = wp[3 * D_MODEL];
      const unsigned long long pv =
          (unsigned long long)f2bf(a0)
        | ((unsigned long long)f2bf(a1) << 16)
        | ((unsigned long long)f2bf(a2) << 32)
        | ((unsigned long long)f2bf(a3) << 48);
      *((unsigned long long*)&Ws[bn][kb]) = pv;
    }
    __syncthreads();

    const int fr = lane & 15;
    const int fc = (lane >> 4) * 8;
    bf16x8 af[4], bfv[4];
#pragma unroll
    for (int mb = 0; mb < 4; ++mb) af[mb]  = *(const bf16x8*)&Xs[wm + mb * 16 + fr][fc];
#pragma unroll
    for (int nb = 0; nb < 4; ++nb) bfv[nb] = *(const bf16x8*)&Ws[wn + nb * 16 + fr][fc];
#pragma unroll
    for (int mb = 0; mb < 4; ++mb)
#pragma unroll
      for (int nb = 0; nb < 4; ++nb)
        acc[mb][nb] = __builtin_amdgcn_mfma_f32_16x16x32_bf16(af[mb], bfv[nb], acc[mb][nb], 0, 0, 0);
    __syncthreads();
  }

  // epilogue: out[tok] += gate * (acc + b2)
  float bias[4];
#pragma unroll
  for (int nb = 0; nb < 4; ++nb)
    bias[nb] = b2[e * D_MODEL + n0 + wn + nb * 16 + (lane & 15)];

#pragma unroll
  for (int mb = 0; mb < 4; ++mb)
#pragma unroll
    for (int r = 0; r < 4; ++r) {
      const int rowT = wm + mb * 16 + (lane >> 4) * 4 + r;
      if (m0 + rowT < cnt) {
        const int sidx = e * NTOK + m0 + rowT;
        const int tok  = rowlist[sidx];
        const float g  = gatelist[sidx];
        float* orow = out + (size_t)tok * D_MODEL;
#pragma unroll
        for (int nb = 0; nb < 4; ++nb) {
          const int col = n0 + wn + nb * 16 + (lane & 15);
          atomicAdd(&orow[col], g * (acc[mb][nb][r] + bias[nb]));
        }
      }
    }
}

// ---------------- launch ----------------
extern "C" void kernel_launch(void* const* d_in, const int* in_sizes, int n_in,
                              void* d_out, int out_size, void* d_ws, size_t ws_size,
                              hipStream_t stream) {
  const float* X  = (const float*)d_in[0];
  const float* Wr = (const float*)d_in[1];
  const float* br = (const float*)d_in[2];
  const float* W1 = (const float*)d_in[3];
  const float* b1 = (const float*)d_in[4];
  const float* W2 = (const float*)d_in[5];
  const float* b2 = (const float*)d_in[6];
  float* out = (float*)d_out;

  char* w = (char*)d_ws;
  int*   topIdx   = (int*)(w);                                   // 32 KB
  float* topGate  = (float*)(w + (32 << 10));                    // 32 KB
  int*   counts   = (int*)(w + (64 << 10));                      // 64 B
  int*   bankOff  = (int*)(w + (64 << 10) + 256);                // 68 B
  int*   rowlist  = (int*)(w + (66 << 10));                      // 256 KB
  float* gatelist = (float*)(w + (66 << 10) + NBANKS * NTOK * 4);// 256 KB
  unsigned short* H = (unsigned short*)(w + (1 << 20));          // 64 MiB

  const size_t needed = (size_t)(1 << 20) + (size_t)(NTOK * 2) * D_HIDDEN * 2;
  if (ws_size < needed) return;  // fail loudly via absmax rather than corrupt memory

  zero_out_k<<<dim3(4096), dim3(256), 0, stream>>>((float4*)out, counts);
  router_k<<<dim3(NTOK), dim3(64), 0, stream>>>(X, Wr, br, topIdx, topGate);
  build_lists_k<<<dim3(16), dim3(256), 0, stream>>>(topIdx, topGate, counts, rowlist, gatelist);
  scan_k<<<dim3(1), dim3(64), 0, stream>>>(counts, bankOff);
  gemm1_k<<<dim3(D_HIDDEN / BN, NTOK / BM, NBANKS), dim3(256), 0, stream>>>(
      X, W1, b1, counts, bankOff, rowlist, H);
  gemm2_k<<<dim3(D_MODEL / BN, NTOK / BM, NBANKS), dim3(256), 0, stream>>>(
      H, W2, b2, counts, bankOff, rowlist, gatelist, out);
}

// Round 2
// 496.002 us; speedup vs baseline: 1.0058x; 1.0058x over previous
//
#include <hip/hip_runtime.h>
#include <stdint.h>

#define D_MODEL   1024
#define D_HIDDEN  4096
#define NBANKS    16
#define NTOK      4096      // 4 * 1024 tokens

#define BM 128
#define BN 128
#define BK 32

typedef __attribute__((ext_vector_type(8))) short bf16x8;
typedef __attribute__((ext_vector_type(4))) float f32x4;
typedef __attribute__((ext_vector_type(4))) unsigned int u32x4;
typedef __attribute__((ext_vector_type(2))) unsigned int u32x2;

__device__ __forceinline__ unsigned short f2bf(float f) {
  unsigned u = __builtin_bit_cast(unsigned, f);
  u += 0x7FFFu + ((u >> 16) & 1u);      // round-to-nearest-even
  return (unsigned short)(u >> 16);
}

// packed f32 pair -> 2x bf16 in one u32 (dst.lo = cvt(lo), dst.hi = cvt(hi))
__device__ __forceinline__ unsigned cvtpk(float lo, float hi) {
  unsigned r;
  asm("v_cvt_pk_bf16_f32 %0, %1, %2" : "=v"(r) : "v"(lo), "v"(hi));
  return r;
}

// swizzled LDS element index for a [128][32] bf16 tile (row stride 64B):
// 16B chunk index c is XORed with (row>>1)&3 -> even bank spread on b128
// reads (16 rows x same chunk) and staging writes.
__device__ __forceinline__ int swz(int row, int col) {
  const int c = (col >> 3) ^ ((row >> 1) & 3);
  return row * 32 + c * 8 + (col & 7);
}

// ---------------- zero output + counts ----------------
__global__ __launch_bounds__(256) void zero_out_k(float4* __restrict__ out4,
                                                  int* __restrict__ counts) {
  size_t i = (size_t)blockIdx.x * 256 + threadIdx.x;
  out4[i] = make_float4(0.f, 0.f, 0.f, 0.f);
  if (blockIdx.x == 0 && threadIdx.x < NBANKS) counts[threadIdx.x] = 0;
}

// ---------------- router: softmax over 16 banks, top-2 ----------------
__global__ __launch_bounds__(64) void router_k(const float* __restrict__ x,
                                               const float* __restrict__ Wr,
                                               const float* __restrict__ br,
                                               int* __restrict__ topIdx,
                                               float* __restrict__ topGate) {
  const int t = blockIdx.x;
  const int l = threadIdx.x;
  const float* xr = x + (size_t)t * D_MODEL;

  float acc[NBANKS];
#pragma unroll
  for (int e = 0; e < NBANKS; ++e) acc[e] = 0.f;

  for (int d = l; d < D_MODEL; d += 64) {
    const float xv = xr[d];
    const float* wrow = Wr + (size_t)d * NBANKS;
#pragma unroll
    for (int e = 0; e < NBANKS; ++e) acc[e] += xv * wrow[e];
  }
#pragma unroll
  for (int e = 0; e < NBANKS; ++e) {
#pragma unroll
    for (int m = 1; m < 64; m <<= 1) acc[e] += __shfl_xor(acc[e], m, 64);
  }
#pragma unroll
  for (int e = 0; e < NBANKS; ++e) acc[e] += br[e];

  if (l == 0) {
    float mx = acc[0];
#pragma unroll
    for (int e = 1; e < NBANKS; ++e) mx = fmaxf(mx, acc[e]);
    float p[NBANKS];
    float s = 0.f;
#pragma unroll
    for (int e = 0; e < NBANKS; ++e) { p[e] = expf(acc[e] - mx); s += p[e]; }
    int i0 = 0; float v0 = p[0];
#pragma unroll
    for (int e = 1; e < NBANKS; ++e) if (p[e] > v0) { v0 = p[e]; i0 = e; }
    int i1 = -1; float v1 = -1.f;
#pragma unroll
    for (int e = 0; e < NBANKS; ++e) if (e != i0 && p[e] > v1) { v1 = p[e]; i1 = e; }
    const float inv = 1.f / s;
    topIdx[2 * t]     = i0;
    topIdx[2 * t + 1] = i1;
    topGate[2 * t]     = v0 * inv;
    topGate[2 * t + 1] = v1 * inv;
  }
}

// ---------------- build per-bank token lists ----------------
__global__ __launch_bounds__(256) void build_lists_k(const int* __restrict__ topIdx,
                                                     const float* __restrict__ topGate,
                                                     int* __restrict__ counts,
                                                     int* __restrict__ rowlist,
                                                     float* __restrict__ gatelist) {
  const int t = blockIdx.x * 256 + threadIdx.x;
  if (t >= NTOK) return;
#pragma unroll
  for (int k = 0; k < 2; ++k) {
    const int e = topIdx[2 * t + k];
    const int p = atomicAdd(&counts[e], 1);
    rowlist[e * NTOK + p]  = t;
    gatelist[e * NTOK + p] = topGate[2 * t + k];
  }
}

__global__ void scan_k(const int* __restrict__ counts, int* __restrict__ bankOff) {
  if (threadIdx.x == 0) {
    int s = 0;
#pragma unroll
    for (int e = 0; e < NBANKS; ++e) { bankOff[e] = s; s += counts[e]; }
    bankOff[NBANKS] = s;
  }
}

// ---------------- GEMM1: H = relu(gather(X) @ W1[e] + b1[e]) ----------------
__global__ __launch_bounds__(256) void gemm1_k(const float* __restrict__ X,
                                               const float* __restrict__ W1,
                                               const float* __restrict__ b1,
                                               const int* __restrict__ counts,
                                               const int* __restrict__ bankOff,
                                               const int* __restrict__ rowlist,
                                               unsigned short* __restrict__ H) {
  const int e   = blockIdx.z;
  const int cnt = counts[e];
  const int m0  = blockIdx.y * BM;
  if (m0 >= cnt) return;
  const int n0  = blockIdx.x * BN;

  const int tid  = threadIdx.x;
  const int lane = tid & 63;
  const int w    = tid >> 6;
  const int wm   = (w >> 1) * 64;
  const int wn   = (w & 1) * 64;

  __shared__ unsigned short Xs[BM * BK];   // swizzled [128][32]
  __shared__ unsigned short Ws[BN * BK];   // swizzled [128][32] (n-major)

  // A staging: 2 threads per row, 16 f32 each
  const int ar = tid >> 1;
  const int ak = (tid & 1) * 16;
  const int gi = min(m0 + ar, cnt - 1);
  const int tok = rowlist[e * NTOK + gi];
  const float* Asrc = X + (size_t)tok * D_MODEL + ak;
  unsigned short* xsw0 = &Xs[swz(ar, ak)];
  unsigned short* xsw1 = &Xs[swz(ar, ak + 8)];

  // B staging: 4x4 micro-tile transpose; thread covers n4..n4+3 x k4..k4+3
  const int bn4 = (tid & 31) * 4;
  const int bk4 = (tid >> 5) * 4;
  const float* Bsrc = W1 + (size_t)e * D_MODEL * D_HIDDEN + (size_t)bk4 * D_HIDDEN + n0 + bn4;
  unsigned short* wsw0 = &Ws[swz(bn4 + 0, bk4)];
  unsigned short* wsw1 = &Ws[swz(bn4 + 1, bk4)];
  unsigned short* wsw2 = &Ws[swz(bn4 + 2, bk4)];
  unsigned short* wsw3 = &Ws[swz(bn4 + 3, bk4)];

  // fragment read pointers (loop-invariant)
  const int fr = lane & 15;
  const int fc = (lane >> 4) * 8;
  const unsigned short* arp[4];
  const unsigned short* brp[4];
#pragma unroll
  for (int i = 0; i < 4; ++i) {
    arp[i] = &Xs[swz(wm + i * 16 + fr, fc)];
    brp[i] = &Ws[swz(wn + i * 16 + fr, fc)];
  }

  f32x4 acc[4][4];
#pragma unroll
  for (int i = 0; i < 4; ++i)
#pragma unroll
    for (int j = 0; j < 4; ++j)
#pragma unroll
      for (int r = 0; r < 4; ++r) acc[i][j][r] = 0.f;

  for (int k0 = 0; k0 < D_MODEL; k0 += BK) {
    // --- stage A: 16 f32 -> 8 cvt_pk -> 2 b128 stores
    {
      const float4* s4 = (const float4*)(Asrc + k0);
      const float4 f0 = s4[0], f1 = s4[1], f2 = s4[2], f3 = s4[3];
      u32x4 v0, v1;
      v0[0] = cvtpk(f0.x, f0.y); v0[1] = cvtpk(f0.z, f0.w);
      v0[2] = cvtpk(f1.x, f1.y); v0[3] = cvtpk(f1.z, f1.w);
      v1[0] = cvtpk(f2.x, f2.y); v1[1] = cvtpk(f2.z, f2.w);
      v1[2] = cvtpk(f3.x, f3.y); v1[3] = cvtpk(f3.z, f3.w);
      *((u32x4*)xsw0) = v0;
      *((u32x4*)xsw1) = v1;
    }
    // --- stage B: 4x float4 (coalesced along n) -> transpose -> 4 b64 stores
    {
      const float* wp = Bsrc + (size_t)k0 * D_HIDDEN;
      const float4 r0 = *(const float4*)(wp);
      const float4 r1 = *(const float4*)(wp + D_HIDDEN);
      const float4 r2 = *(const float4*)(wp + 2 * D_HIDDEN);
      const float4 r3 = *(const float4*)(wp + 3 * D_HIDDEN);
      u32x2 t0, t1, t2, t3;
      t0[0] = cvtpk(r0.x, r1.x); t0[1] = cvtpk(r2.x, r3.x);
      t1[0] = cvtpk(r0.y, r1.y); t1[1] = cvtpk(r2.y, r3.y);
      t2[0] = cvtpk(r0.z, r1.z); t2[1] = cvtpk(r2.z, r3.z);
      t3[0] = cvtpk(r0.w, r1.w); t3[1] = cvtpk(r2.w, r3.w);
      *((u32x2*)wsw0) = t0;
      *((u32x2*)wsw1) = t1;
      *((u32x2*)wsw2) = t2;
      *((u32x2*)wsw3) = t3;
    }
    __syncthreads();

    bf16x8 af[4], bfv[4];
#pragma unroll
    for (int mb = 0; mb < 4; ++mb) af[mb]  = *(const bf16x8*)arp[mb];
#pragma unroll
    for (int nb = 0; nb < 4; ++nb) bfv[nb] = *(const bf16x8*)brp[nb];
#pragma unroll
    for (int mb = 0; mb < 4; ++mb)
#pragma unroll
      for (int nb = 0; nb < 4; ++nb)
        acc[mb][nb] = __builtin_amdgcn_mfma_f32_16x16x32_bf16(af[mb], bfv[nb], acc[mb][nb], 0, 0, 0);
    __syncthreads();
  }

  // epilogue: relu(acc + b1) -> H (bf16)
  const int hb = bankOff[e] + m0;
#pragma unroll
  for (int nb = 0; nb < 4; ++nb) {
    const int col = n0 + wn + nb * 16 + (lane & 15);
    const float bias = b1[e * D_HIDDEN + col];
#pragma unroll
    for (int mb = 0; mb < 4; ++mb)
#pragma unroll
      for (int r = 0; r < 4; ++r) {
        const int rowT = wm + mb * 16 + (lane >> 4) * 4 + r;
        if (m0 + rowT < cnt) {
          float v = acc[mb][nb][r] + bias;
          v = fmaxf(v, 0.f);
          H[(size_t)(hb + rowT) * D_HIDDEN + col] = f2bf(v);
        }
      }
  }
}

// ---------------- GEMM2: out += gate * (H @ W2[e] + b2[e]) ----------------
__global__ __launch_bounds__(256) void gemm2_k(const unsigned short* __restrict__ H,
                                               const float* __restrict__ W2,
                                               const float* __restrict__ b2,
                                               const int* __restrict__ counts,
                                               const int* __restrict__ bankOff,
                                               const int* __restrict__ rowlist,
                                               const float* __restrict__ gatelist,
                                               float* __restrict__ out) {
  const int e   = blockIdx.z;
  const int cnt = counts[e];
  const int m0  = blockIdx.y * BM;
  if (m0 >= cnt) return;
  const int n0  = blockIdx.x * BN;

  const int tid  = threadIdx.x;
  const int lane = tid & 63;
  const int w    = tid >> 6;
  const int wm   = (w >> 1) * 64;
  const int wn   = (w & 1) * 64;

  __shared__ unsigned short Xs[BM * BK];
  __shared__ unsigned short Ws[BN * BK];

  const int ar = tid >> 1;
  const int ak = (tid & 1) * 16;
  const int hb = bankOff[e];
  const int gi = hb + min(m0 + ar, cnt - 1);
  const unsigned short* Asrc = H + (size_t)gi * D_HIDDEN + ak;
  unsigned short* xsw0 = &Xs[swz(ar, ak)];
  unsigned short* xsw1 = &Xs[swz(ar, ak + 8)];

  const int bn4 = (tid & 31) * 4;
  const int bk4 = (tid >> 5) * 4;
  const float* Bsrc = W2 + (size_t)e * D_HIDDEN * D_MODEL + (size_t)bk4 * D_MODEL + n0 + bn4;
  unsigned short* wsw0 = &Ws[swz(bn4 + 0, bk4)];
  unsigned short* wsw1 = &Ws[swz(bn4 + 1, bk4)];
  unsigned short* wsw2 = &Ws[swz(bn4 + 2, bk4)];
  unsigned short* wsw3 = &Ws[swz(bn4 + 3, bk4)];

  const int fr = lane & 15;
  const int fc = (lane >> 4) * 8;
  const unsigned short* arp[4];
  const unsigned short* brp[4];
#pragma unroll
  for (int i = 0; i < 4; ++i) {
    arp[i] = &Xs[swz(wm + i * 16 + fr, fc)];
    brp[i] = &Ws[swz(wn + i * 16 + fr, fc)];
  }

  f32x4 acc[4][4];
#pragma unroll
  for (int i = 0; i < 4; ++i)
#pragma unroll
    for (int j = 0; j < 4; ++j)
#pragma unroll
      for (int r = 0; r < 4; ++r) acc[i][j][r] = 0.f;

  for (int k0 = 0; k0 < D_HIDDEN; k0 += BK) {
    // --- stage A: H already bf16, two b128 copies
    *((bf16x8*)xsw0) = *(const bf16x8*)(Asrc + k0);
    *((bf16x8*)xsw1) = *(const bf16x8*)(Asrc + k0 + 8);
    // --- stage B: 4x float4 -> transpose -> 4 b64 stores
    {
      const float* wp = Bsrc + (size_t)k0 * D_MODEL;
      const float4 r0 = *(const float4*)(wp);
      const float4 r1 = *(const float4*)(wp + D_MODEL);
      const float4 r2 = *(const float4*)(wp + 2 * D_MODEL);
      const float4 r3 = *(const float4*)(wp + 3 * D_MODEL);
      u32x2 t0, t1, t2, t3;
      t0[0] = cvtpk(r0.x, r1.x); t0[1] = cvtpk(r2.x, r3.x);
      t1[0] = cvtpk(r0.y, r1.y); t1[1] = cvtpk(r2.y, r3.y);
      t2[0] = cvtpk(r0.z, r1.z); t2[1] = cvtpk(r2.z, r3.z);
      t3[0] = cvtpk(r0.w, r1.w); t3[1] = cvtpk(r2.w, r3.w);
      *((u32x2*)wsw0) = t0;
      *((u32x2*)wsw1) = t1;
      *((u32x2*)wsw2) = t2;
      *((u32x2*)wsw3) = t3;
    }
    __syncthreads();

    bf16x8 af[4], bfv[4];
#pragma unroll
    for (int mb = 0; mb < 4; ++mb) af[mb]  = *(const bf16x8*)arp[mb];
#pragma unroll
    for (int nb = 0; nb < 4; ++nb) bfv[nb] = *(const bf16x8*)brp[nb];
#pragma unroll
    for (int mb = 0; mb < 4; ++mb)
#pragma unroll
      for (int nb = 0; nb < 4; ++nb)
        acc[mb][nb] = __builtin_amdgcn_mfma_f32_16x16x32_bf16(af[mb], bfv[nb], acc[mb][nb], 0, 0, 0);
    __syncthreads();
  }

  // epilogue: out[tok] += gate * (acc + b2)
  float bias[4];
#pragma unroll
  for (int nb = 0; nb < 4; ++nb)
    bias[nb] = b2[e * D_MODEL + n0 + wn + nb * 16 + (lane & 15)];

#pragma unroll
  for (int mb = 0; mb < 4; ++mb)
#pragma unroll
    for (int r = 0; r < 4; ++r) {
      const int rowT = wm + mb * 16 + (lane >> 4) * 4 + r;
      if (m0 + rowT < cnt) {
        const int sidx = e * NTOK + m0 + rowT;
        const int tok  = rowlist[sidx];
        const float g  = gatelist[sidx];
        float* orow = out + (size_t)tok * D_MODEL;
#pragma unroll
        for (int nb = 0; nb < 4; ++nb) {
          const int col = n0 + wn + nb * 16 + (lane & 15);
          atomicAdd(&orow[col], g * (acc[mb][nb][r] + bias[nb]));
        }
      }
    }
}

// ---------------- launch ----------------
extern "C" void kernel_launch(void* const* d_in, const int* in_sizes, int n_in,
                              void* d_out, int out_size, void* d_ws, size_t ws_size,
                              hipStream_t stream) {
  const float* X  = (const float*)d_in[0];
  const float* Wr = (const float*)d_in[1];
  const float* br = (const float*)d_in[2];
  const float* W1 = (const float*)d_in[3];
  const float* b1 = (const float*)d_in[4];
  const float* W2 = (const float*)d_in[5];
  const float* b2 = (const float*)d_in[6];
  float* out = (float*)d_out;

  char* w = (char*)d_ws;
  int*   topIdx   = (int*)(w);                                   // 32 KB
  float* topGate  = (float*)(w + (32 << 10));                    // 32 KB
  int*   counts   = (int*)(w + (64 << 10));                      // 64 B
  int*   bankOff  = (int*)(w + (64 << 10) + 256);                // 68 B
  int*   rowlist  = (int*)(w + (66 << 10));                      // 256 KB
  float* gatelist = (float*)(w + (66 << 10) + NBANKS * NTOK * 4);// 256 KB
  unsigned short* H = (unsigned short*)(w + (1 << 20));          // 64 MiB

  const size_t needed = (size_t)(1 << 20) + (size_t)(NTOK * 2) * D_HIDDEN * 2;
  if (ws_size < needed) return;

  zero_out_k<<<dim3(4096), dim3(256), 0, stream>>>((float4*)out, counts);
  router_k<<<dim3(NTOK), dim3(64), 0, stream>>>(X, Wr, br, topIdx, topGate);
  build_lists_k<<<dim3(16), dim3(256), 0, stream>>>(topIdx, topGate, counts, rowlist, gatelist);
  scan_k<<<dim3(1), dim3(64), 0, stream>>>(counts, bankOff);
  gemm1_k<<<dim3(D_HIDDEN / BN, NTOK / BM, NBANKS), dim3(256), 0, stream>>>(
      X, W1, b1, counts, bankOff, rowlist, H);
  gemm2_k<<<dim3(D_MODEL / BN, NTOK / BM, NBANKS), dim3(256), 0, stream>>>(
      H, W2, b2, counts, bankOff, rowlist, gatelist, out);
}